// Round 2
// baseline (242.271 us; speedup 1.0000x reference)
//
#include <hip/hip_runtime.h>
#include <hip/hip_cooperative_groups.h>

namespace cg = cooperative_groups;

#define B_    32
#define S_    64
#define D_    8
#define NE_   512        // S_*D_
#define E_    150000
#define CAP   448        // compacted edges per bin (mean 293, ~9 sigma headroom)
#define EPB   ((E_ + NE_ - 1) / NE_)   // 293 edges binned per block

typedef __attribute__((ext_vector_type(8)))  short  short8;   // 8 bf16 (4 VGPR)
typedef __attribute__((ext_vector_type(16))) float  float16;  // MFMA C/D (16 regs)

__device__ __forceinline__ unsigned short f2bf(float f) {
    union { float f; unsigned int u; } cv; cv.f = f;
    unsigned int u = cv.u;
    return (unsigned short)((u + 0x7fffu + ((u >> 16) & 1u)) >> 16);
}
__device__ __forceinline__ unsigned int pack2bf(float a, float b) {
    return (unsigned int)f2bf(a) | ((unsigned int)f2bf(b) << 16);
}

// ---------------- fused kernel ----------------
// Phase 1 (binning): block bid bins edges [bid*EPB, bid*EPB+EPB) via LDS counts,
//   reserves contiguous payload ranges with one global atomicAdd per nonzero bin,
//   writes compacted payload[bin*CAP + slot].  gcnt[bid] zeroed by block bid.
// Phase 2 (per-bin MFMA): identical math to previous main_mfma.
//   Layer0 (transposed): H^T = Wa(32x16) . X^T(16xn); Layer1: 2 chained K=16 MFMAs.
//   C/D layout: col = lane&31, row = (reg&3) + 8*(reg>>2) + 4*(lane>>5)
//   C->B-frag reshuffle in registers via v_permlane32_swap_b32.

#define TILE_COMPUTE(bXv, pvv, vldv)                                            \
  {                                                                             \
    float16 c0;                                                                 \
    _Pragma("unroll")                                                           \
    for (int r = 0; r < 16; ++r)                                                \
        c0[r] = bias0s[(r & 3) + 8 * (r >> 2) + 4 * q];                         \
    c0 = __builtin_amdgcn_mfma_f32_32x32x16_bf16(aWa, (bXv), c0, 0, 0, 0);      \
    unsigned Pw[8];                                                             \
    _Pragma("unroll")                                                           \
    for (int j = 0; j < 8; ++j)                                                 \
        Pw[j] = pack2bf(fmaxf(c0[2 * j], 0.f), fmaxf(c0[2 * j + 1], 0.f));      \
    asm("v_permlane32_swap_b32 %0, %1" : "+v"(Pw[0]), "+v"(Pw[2]));             \
    asm("v_permlane32_swap_b32 %0, %1" : "+v"(Pw[1]), "+v"(Pw[3]));             \
    asm("v_permlane32_swap_b32 %0, %1" : "+v"(Pw[4]), "+v"(Pw[6]));             \
    asm("v_permlane32_swap_b32 %0, %1" : "+v"(Pw[5]), "+v"(Pw[7]));             \
    union { unsigned u[4]; short8 s; } H0c, H1c;                                \
    H0c.u[0] = Pw[0]; H0c.u[1] = Pw[1]; H0c.u[2] = Pw[2]; H0c.u[3] = Pw[3];     \
    H1c.u[0] = Pw[4]; H1c.u[1] = Pw[5]; H1c.u[2] = Pw[6]; H1c.u[3] = Pw[7];     \
    float16 c1;                                                                 \
    _Pragma("unroll")                                                           \
    for (int r = 0; r < 16; ++r)                                                \
        c1[r] = bias1s[(r & 3) + 8 * (r >> 2) + 4 * q];                         \
    c1 = __builtin_amdgcn_mfma_f32_32x32x16_bf16(aWb0, H0c.s, c1, 0, 0, 0);     \
    c1 = __builtin_amdgcn_mfma_f32_32x32x16_bf16(aWb1, H1c.s, c1, 0, 0, 0);     \
    if (vldv) {                                                                 \
        const int b_e = ((pvv) >> 16) & 31;                                     \
        _Pragma("unroll")                                                       \
        for (int r = 0; r < 16; ++r)                                            \
            atomicAdd(&acc[b_e][(r & 3) + 8 * (r >> 2) + 4 * q],                \
                      fmaxf(c1[r], 0.f));                                       \
        if (q == 0) atomicAdd(&cnts[b_e], 1.f);                                 \
    }                                                                           \
  }

__global__ __launch_bounds__(512, 4)
void fused(const float* __restrict__ nf,
           const float* __restrict__ iw0, const float* __restrict__ ib0,
           const float* __restrict__ iw1, const float* __restrict__ ib1,
           const float* __restrict__ ow0, const float* __restrict__ ob0,
           const float* __restrict__ ow1, const float* __restrict__ ob1,
           const int* __restrict__ inc,
           int* __restrict__ gcnt, int* __restrict__ payload,
           float* __restrict__ out) {
    const int bid  = blockIdx.x;          // == eidx (bin)
    const int tid  = threadIdx.x;
    const int lane = tid & 63;
    const int wav  = tid >> 6;            // 0..7
    const int e32  = lane & 31;           // edge-in-tile / A-row
    const int q    = lane >> 5;           // k-half selector

    __shared__ float acc[32][33];
    __shared__ float hb[32][33];
    __shared__ float cnts[32];
    __shared__ float q0t[32 * 33];        // [k][o] transposed, pad 33
    __shared__ float q1t[32 * 17];        // [k][o] transposed, pad 17
    __shared__ float qb0s[32], qb1s[16];
    __shared__ float bias0s[32], bias1s[32];
    __shared__ int   lcount[NE_];
    __shared__ int   lbase[NE_];

    cg::grid_group grid = cg::this_grid();

    // --- zero my gcnt entry (visible after grid sync #1) ---
    if (tid == 0) gcnt[bid] = 0;

    // --- per-lane A-frags (weights, packed bf16) — independent, issue early ---
    short8 aWa, aWb0, aWb1;
    {
        const float* wa = iw0 + (size_t)bid * 512 + e32 * 16 + q * 8;
        float4 u0 = ((const float4*)wa)[0], u1 = ((const float4*)wa)[1];
        unsigned int p[4] = { pack2bf(u0.x,u0.y), pack2bf(u0.z,u0.w),
                              pack2bf(u1.x,u1.y), pack2bf(u1.z,u1.w) };
        aWa = *(short8*)p;
    }
    {
        const float* wb = iw1 + (size_t)bid * 1024 + e32 * 32 + q * 8;
        float4 u0 = ((const float4*)wb)[0], u1 = ((const float4*)wb)[1];
        unsigned int p[4] = { pack2bf(u0.x,u0.y), pack2bf(u0.z,u0.w),
                              pack2bf(u1.x,u1.y), pack2bf(u1.z,u1.w) };
        aWb0 = *(short8*)p;
        const float* wb2 = wb + 16;
        float4 u2 = ((const float4*)wb2)[0], u3 = ((const float4*)wb2)[1];
        unsigned int p2[4] = { pack2bf(u2.x,u2.y), pack2bf(u2.z,u2.w),
                               pack2bf(u3.x,u3.y), pack2bf(u3.z,u3.w) };
        aWb1 = *(short8*)p2;
    }

    // --- staging (out-weights transposed, biases, acc zero) ---
    for (int i = tid; i < 1024; i += 512) {
        const int o = i >> 5, k = i & 31;
        q0t[k * 33 + o] = ow0[(size_t)bid * 1024 + i];
    }
    { const int o = tid >> 5, k = tid & 31;
      q1t[k * 17 + o] = ow1[(size_t)bid * 512 + tid]; }
    if (tid < 32)       { bias0s[tid] = ib0[bid * 32 + tid]; cnts[tid] = 0.f; }
    else if (tid < 64)  bias1s[tid - 32] = ib1[bid * 32 + (tid - 32)];
    else if (tid < 96)  qb0s[tid - 64] = ob0[bid * 32 + (tid - 64)];
    else if (tid < 112) qb1s[tid - 96] = ob1[bid * 16 + (tid - 96)];
    for (int i = tid; i < 32 * 33; i += 512) ((float*)acc)[i] = 0.f;

    // --- phase 1a: local binning of my edge slice (LDS only) ---
    if (tid < NE_) lcount[tid] = 0;
    __syncthreads();

    const int e = bid * EPB + tid;
    int ei = -1, lp = 0, pl = 0;
    if (tid < EPB && e < E_) {
        const int4 c = ((const int4*)inc)[e];   // c0=batch c1=node c2 c3
        ei = c.z * D_ + c.w;
        pl = (c.x << 16) | (c.y * S_ + c.z);
        lp = atomicAdd(&lcount[ei], 1);         // LDS atomic only
    }
    __syncthreads();

    grid.sync();   // #1: all gcnt entries zeroed

    // --- phase 1b: reserve ranges + compacted scatter ---
    if (tid < NE_) {
        const int c = lcount[tid];
        lbase[tid] = c ? atomicAdd(&gcnt[tid], c) : 0;   // 1 RMW per (blk,bin)
    }
    __syncthreads();
    if (ei >= 0) {
        const int s = lbase[ei] + lp;
        if (s < CAP) payload[ei * CAP + s] = pl;
    }

    grid.sync();   // #2: all payload writes + counts visible

    // --- phase 2: per-bin MFMA (2 tiles per wave, straight-line) ---
    const int n = min(gcnt[bid], CAP);
    const int ntiles = (n + 31) >> 5;       // <= 14
    const bool h0 = wav < ntiles;
    const bool h1 = (wav + 8) < ntiles;
    int  pv0 = 0, pv1 = 0;
    bool v0 = false, v1 = false;
    short8 bX0 = {}, bX1 = {};
    if (h0) {
        const int s = (wav << 5) + e32;
        v0 = s < n;
        pv0 = payload[bid * CAP + (v0 ? s : n - 1)];
    }
    if (h1) {
        const int s = ((wav + 8) << 5) + e32;
        v1 = s < n;
        pv1 = payload[bid * CAP + (v1 ? s : n - 1)];
    }
    if (h0) {
        const float4* xp = (const float4*)(nf + (size_t)(pv0 & 0xFFFF) * 16 + q * 8);
        float4 u0 = xp[0], u1 = xp[1];
        unsigned int pk[4] = { pack2bf(u0.x,u0.y), pack2bf(u0.z,u0.w),
                               pack2bf(u1.x,u1.y), pack2bf(u1.z,u1.w) };
        bX0 = *(short8*)pk;
    }
    if (h1) {
        const float4* xp = (const float4*)(nf + (size_t)(pv1 & 0xFFFF) * 16 + q * 8);
        float4 u0 = xp[0], u1 = xp[1];
        unsigned int pk[4] = { pack2bf(u0.x,u0.y), pack2bf(u0.z,u0.w),
                               pack2bf(u1.x,u1.y), pack2bf(u1.z,u1.w) };
        bX1 = *(short8*)pk;
    }

    if (h0) TILE_COMPUTE(bX0, pv0, v0);
    if (h1) TILE_COMPUTE(bX1, pv1, v1);
    __syncthreads();

    // --- mean + out layer 0: thread -> (b = tid>>4, outputs 2*(tid&15)..) ---
    {
        const int b  = tid >> 4;
        const int j  = tid & 15;
        const float cv  = cnts[b];
        const float inv = cv > 0.f ? 1.0f / cv : 0.0f;
        #pragma unroll
        for (int s = 0; s < 2; ++s) {
            const int oo = j * 2 + s;
            float d = 0.f;
            #pragma unroll
            for (int k = 0; k < 32; ++k) d = fmaf(q0t[k * 33 + oo], acc[b][k], d);
            hb[b][oo] = fmaxf(fmaf(d, inv, qb0s[oo]), 0.f);
        }
    }
    __syncthreads();

    // --- out layer 1: thread -> (b = tid>>4, o = tid&15) ---
    {
        const int b = tid >> 4;
        const int o = tid & 15;
        float d = qb1s[o];
        #pragma unroll
        for (int k = 0; k < 32; ++k) d = fmaf(q1t[k * 17 + o], hb[b][k], d);
        out[((size_t)b * NE_ + bid) * 16 + o] = fmaxf(d, 0.f);
    }
}

extern "C" void kernel_launch(void* const* d_in, const int* in_sizes, int n_in,
                              void* d_out, int out_size, void* d_ws, size_t ws_size,
                              hipStream_t stream) {
    const float* nf  = (const float*)d_in[0];
    const float* iw0 = (const float*)d_in[1];
    const float* ib0 = (const float*)d_in[2];
    const float* iw1 = (const float*)d_in[3];
    const float* ib1 = (const float*)d_in[4];
    const float* ow0 = (const float*)d_in[5];
    const float* ob0 = (const float*)d_in[6];
    const float* ow1 = (const float*)d_in[7];
    const float* ob1 = (const float*)d_in[8];
    const int*   inc = (const int*)d_in[9];

    int*   gcnt    = (int*)d_ws;                         // [NE_]
    int*   payload = (int*)((char*)d_ws + 4096);         // [NE_][CAP]
    float* outp    = (float*)d_out;

    void* kargs[] = { (void*)&nf,  (void*)&iw0, (void*)&ib0, (void*)&iw1,
                      (void*)&ib1, (void*)&ow0, (void*)&ob0, (void*)&ow1,
                      (void*)&ob1, (void*)&inc, (void*)&gcnt, (void*)&payload,
                      (void*)&outp };
    hipLaunchCooperativeKernel((const void*)fused, dim3(NE_), dim3(512),
                               kargs, 0, stream);
}

// Round 3
// 119.357 us; speedup vs baseline: 2.0298x; 2.0298x over previous
//
#include <hip/hip_runtime.h>

#define B_    32
#define S_    64
#define D_    8
#define NE_   512        // S_*D_
#define E_    150000
#define CAP   448        // compacted edges per bin (mean 293, ~9 sigma headroom)

// scatter: 37 blocks x 1024 threads x 4 edges = 151552 slots >= E_
#define SC_BLK   1024
#define SC_EPT   4
#define SC_EPB   (SC_BLK * SC_EPT)                 // 4096
#define SC_GRID  ((E_ + SC_EPB - 1) / SC_EPB)      // 37

#define GC_PITCH 32     // ints per bin counter: one 128B line per bin (kills RMW serialization)

typedef __attribute__((ext_vector_type(8)))  short  short8;   // 8 bf16 (4 VGPR)
typedef __attribute__((ext_vector_type(16))) float  float16;  // MFMA C/D (16 regs)

__device__ __forceinline__ unsigned short f2bf(float f) {
    union { float f; unsigned int u; } cv; cv.f = f;
    unsigned int u = cv.u;
    return (unsigned short)((u + 0x7fffu + ((u >> 16) & 1u)) >> 16);
}
__device__ __forceinline__ unsigned int pack2bf(float a, float b) {
    return (unsigned int)f2bf(a) | ((unsigned int)f2bf(b) << 16);
}

// ---------------- CSR scatter: block-aggregated, line-padded global atomics ----
__global__ __launch_bounds__(SC_BLK)
void scatter_csr(const int* __restrict__ inc,
                 int* __restrict__ gcnt,        // [NE_ * GC_PITCH], zeroed
                 int* __restrict__ payload) {   // [NE_][CAP]
    __shared__ int lcount[NE_];
    __shared__ int lbase[NE_];
    const int tid = threadIdx.x;

    if (tid < NE_) lcount[tid] = 0;
    __syncthreads();

    int ei[SC_EPT], lp[SC_EPT], pl[SC_EPT];
    #pragma unroll
    for (int i = 0; i < SC_EPT; ++i) {
        const int e = blockIdx.x * SC_EPB + i * SC_BLK + tid;   // coalesced
        ei[i] = -1;
        if (e < E_) {
            const int4 c = ((const int4*)inc)[e];   // c0=batch c1=node c2 c3
            ei[i] = c.z * D_ + c.w;
            pl[i] = (c.x << 16) | (c.y * S_ + c.z);
            lp[i] = atomicAdd(&lcount[ei[i]], 1);   // LDS atomic only
        }
    }
    __syncthreads();

    if (tid < NE_) {
        const int c = lcount[tid];
        // one device RMW per (block,bin); each bin counter on its own cache line
        lbase[tid] = c ? atomicAdd(&gcnt[tid * GC_PITCH], c) : 0;
    }
    __syncthreads();

    #pragma unroll
    for (int i = 0; i < SC_EPT; ++i) {
        if (ei[i] >= 0) {
            const int s = lbase[ei[i]] + lp[i];
            if (s < CAP) payload[ei[i] * CAP + s] = pl[i];
        }
    }
}

// ---------------- MFMA main kernel ----------------
// Layer0 (transposed): H^T = Wa(32x16) . X^T(16xn); Layer1: 2 chained K=16 MFMAs.
// C/D layout: col = lane&31, row = (reg&3) + 8*(reg>>2) + 4*(lane>>5)
// C->B-frag reshuffle in registers via v_permlane32_swap_b32.
// Branch-free: both tiles always computed; payload/nf loads unconditional
// (slot bounded by construction, row is 16-bit so always inside nf's 65536 rows);
// validity applied only at the LDS-atomic accumulation.

#define TILE_COMPUTE(bXv, pvv, vldv)                                            \
  {                                                                             \
    float16 c0;                                                                 \
    _Pragma("unroll")                                                           \
    for (int r = 0; r < 16; ++r)                                                \
        c0[r] = bias0s[(r & 3) + 8 * (r >> 2) + 4 * q];                         \
    c0 = __builtin_amdgcn_mfma_f32_32x32x16_bf16(aWa, (bXv), c0, 0, 0, 0);      \
    unsigned Pw[8];                                                             \
    _Pragma("unroll")                                                           \
    for (int j = 0; j < 8; ++j)                                                 \
        Pw[j] = pack2bf(fmaxf(c0[2 * j], 0.f), fmaxf(c0[2 * j + 1], 0.f));      \
    asm("v_permlane32_swap_b32 %0, %1" : "+v"(Pw[0]), "+v"(Pw[2]));             \
    asm("v_permlane32_swap_b32 %0, %1" : "+v"(Pw[1]), "+v"(Pw[3]));             \
    asm("v_permlane32_swap_b32 %0, %1" : "+v"(Pw[4]), "+v"(Pw[6]));             \
    asm("v_permlane32_swap_b32 %0, %1" : "+v"(Pw[5]), "+v"(Pw[7]));             \
    union { unsigned u[4]; short8 s; } H0c, H1c;                                \
    H0c.u[0] = Pw[0]; H0c.u[1] = Pw[1]; H0c.u[2] = Pw[2]; H0c.u[3] = Pw[3];     \
    H1c.u[0] = Pw[4]; H1c.u[1] = Pw[5]; H1c.u[2] = Pw[6]; H1c.u[3] = Pw[7];     \
    float16 c1;                                                                 \
    _Pragma("unroll")                                                           \
    for (int r = 0; r < 16; ++r)                                                \
        c1[r] = bias1s[(r & 3) + 8 * (r >> 2) + 4 * q];                         \
    c1 = __builtin_amdgcn_mfma_f32_32x32x16_bf16(aWb0, H0c.s, c1, 0, 0, 0);     \
    c1 = __builtin_amdgcn_mfma_f32_32x32x16_bf16(aWb1, H1c.s, c1, 0, 0, 0);     \
    if (vldv) {                                                                 \
        const int b_e = ((pvv) >> 16) & 31;                                     \
        _Pragma("unroll")                                                       \
        for (int r = 0; r < 16; ++r)                                            \
            atomicAdd(&acc[b_e][(r & 3) + 8 * (r >> 2) + 4 * q],                \
                      fmaxf(c1[r], 0.f));                                       \
        if (q == 0) atomicAdd(&cnts[b_e], 1.f);                                 \
    }                                                                           \
  }

__global__ __launch_bounds__(512, 4)
void main_mfma(const float* __restrict__ nf,
               const float* __restrict__ iw0, const float* __restrict__ ib0,
               const float* __restrict__ iw1, const float* __restrict__ ib1,
               const float* __restrict__ ow0, const float* __restrict__ ob0,
               const float* __restrict__ ow1, const float* __restrict__ ob1,
               const int* __restrict__ gcnt, const int* __restrict__ payload,
               float* __restrict__ out) {
    const int bid  = blockIdx.x;          // == eidx (bin)
    const int tid  = threadIdx.x;
    const int lane = tid & 63;
    const int wav  = tid >> 6;            // 0..7
    const int e32  = lane & 31;           // edge-in-tile / A-row
    const int q    = lane >> 5;           // k-half selector

    __shared__ float acc[32][33];
    __shared__ float hb[32][33];
    __shared__ float cnts[32];
    __shared__ float q0t[32 * 33];        // [k][o] transposed, pad 33
    __shared__ float q1t[32 * 17];        // [k][o] transposed, pad 17
    __shared__ float qb0s[32], qb1s[16];
    __shared__ float bias0s[32], bias1s[32];

    // --- issue ALL independent global loads first (max MLP, 2-deep chain max) ---
    const int n = min(gcnt[bid * GC_PITCH], CAP);           // independent load

    const int s0 = (wav << 5) + e32;                        // < 256
    const int s1 = s0 + 256;                                // < 512 (may read past n: masked)
    const int pv0 = payload[bid * CAP + s0];                // unconditional
    const int pv1 = payload[bid * CAP + s1];                // unconditional

    short8 aWa, aWb0, aWb1;
    {
        const float* wa = iw0 + (size_t)bid * 512 + e32 * 16 + q * 8;
        float4 u0 = ((const float4*)wa)[0], u1 = ((const float4*)wa)[1];
        unsigned int p[4] = { pack2bf(u0.x,u0.y), pack2bf(u0.z,u0.w),
                              pack2bf(u1.x,u1.y), pack2bf(u1.z,u1.w) };
        aWa = *(short8*)p;
    }
    {
        const float* wb = iw1 + (size_t)bid * 1024 + e32 * 32 + q * 8;
        float4 u0 = ((const float4*)wb)[0], u1 = ((const float4*)wb)[1];
        unsigned int p[4] = { pack2bf(u0.x,u0.y), pack2bf(u0.z,u0.w),
                              pack2bf(u1.x,u1.y), pack2bf(u1.z,u1.w) };
        aWb0 = *(short8*)p;
        const float* wb2 = wb + 16;
        float4 u2 = ((const float4*)wb2)[0], u3 = ((const float4*)wb2)[1];
        unsigned int p2[4] = { pack2bf(u2.x,u2.y), pack2bf(u2.z,u2.w),
                               pack2bf(u3.x,u3.y), pack2bf(u3.z,u3.w) };
        aWb1 = *(short8*)p2;
    }

    // --- gathers: depend only on payload (chain depth 2) ---
    const bool v0 = s0 < n;
    const bool v1 = s1 < n;
    short8 bX0, bX1;
    {
        const float4* xp = (const float4*)(nf + (size_t)(pv0 & 0xFFFF) * 16 + q * 8);
        float4 u0 = xp[0], u1 = xp[1];
        unsigned int pk[4] = { pack2bf(u0.x,u0.y), pack2bf(u0.z,u0.w),
                               pack2bf(u1.x,u1.y), pack2bf(u1.z,u1.w) };
        bX0 = *(short8*)pk;
    }
    {
        const float4* xp = (const float4*)(nf + (size_t)(pv1 & 0xFFFF) * 16 + q * 8);
        float4 u0 = xp[0], u1 = xp[1];
        unsigned int pk[4] = { pack2bf(u0.x,u0.y), pack2bf(u0.z,u0.w),
                               pack2bf(u1.x,u1.y), pack2bf(u1.z,u1.w) };
        bX1 = *(short8*)pk;
    }

    // --- LDS staging (out-weights transposed, biases, acc zero) ---
    for (int i = tid; i < 1024; i += 512) {
        const int o = i >> 5, k = i & 31;
        q0t[k * 33 + o] = ow0[(size_t)bid * 1024 + i];
    }
    { const int o = tid >> 5, k = tid & 31;
      q1t[k * 17 + o] = ow1[(size_t)bid * 512 + tid]; }
    if (tid < 32)       { bias0s[tid] = ib0[bid * 32 + tid]; cnts[tid] = 0.f; }
    else if (tid < 64)  bias1s[tid - 32] = ib1[bid * 32 + (tid - 32)];
    else if (tid < 96)  qb0s[tid - 64] = ob0[bid * 32 + (tid - 64)];
    else if (tid < 112) qb1s[tid - 96] = ob1[bid * 16 + (tid - 96)];
    for (int i = tid; i < 32 * 33; i += 512) ((float*)acc)[i] = 0.f;
    __syncthreads();

    // --- both tiles, straight-line ---
    TILE_COMPUTE(bX0, pv0, v0);
    TILE_COMPUTE(bX1, pv1, v1);
    __syncthreads();

    // --- mean + out layer 0: thread -> (b = tid>>4, outputs 2*(tid&15)..) ---
    {
        const int b  = tid >> 4;
        const int j  = tid & 15;
        const float cv  = cnts[b];
        const float inv = cv > 0.f ? 1.0f / cv : 0.0f;
        #pragma unroll
        for (int s = 0; s < 2; ++s) {
            const int oo = j * 2 + s;
            float d = 0.f;
            #pragma unroll
            for (int k = 0; k < 32; ++k) d = fmaf(q0t[k * 33 + oo], acc[b][k], d);
            hb[b][oo] = fmaxf(fmaf(d, inv, qb0s[oo]), 0.f);
        }
    }
    __syncthreads();

    // --- out layer 1: thread -> (b = tid>>4, o = tid&15) ---
    {
        const int b = tid >> 4;
        const int o = tid & 15;
        float d = qb1s[o];
        #pragma unroll
        for (int k = 0; k < 32; ++k) d = fmaf(q1t[k * 17 + o], hb[b][k], d);
        out[((size_t)b * NE_ + bid) * 16 + o] = fmaxf(d, 0.f);
    }
}

extern "C" void kernel_launch(void* const* d_in, const int* in_sizes, int n_in,
                              void* d_out, int out_size, void* d_ws, size_t ws_size,
                              hipStream_t stream) {
    const float* nf  = (const float*)d_in[0];
    const float* iw0 = (const float*)d_in[1];
    const float* ib0 = (const float*)d_in[2];
    const float* iw1 = (const float*)d_in[3];
    const float* ib1 = (const float*)d_in[4];
    const float* ow0 = (const float*)d_in[5];
    const float* ob0 = (const float*)d_in[6];
    const float* ow1 = (const float*)d_in[7];
    const float* ob1 = (const float*)d_in[8];
    const int*   inc = (const int*)d_in[9];

    int* gcnt    = (int*)d_ws;                                   // [NE_*GC_PITCH] 64 KB
    int* payload = (int*)((char*)d_ws + NE_ * GC_PITCH * 4);     // [NE_][CAP]

    hipMemsetAsync(gcnt, 0, NE_ * GC_PITCH * sizeof(int), stream);
    scatter_csr<<<SC_GRID, SC_BLK, 0, stream>>>(inc, gcnt, payload);
    main_mfma<<<NE_, 512, 0, stream>>>(nf, iw0, ib0, iw1, ib1, ow0, ob0, ow1, ob1,
                                       gcnt, payload, (float*)d_out);
}